// Round 9
// baseline (687.016 us; speedup 1.0000x reference)
//
#include <hip/hip_runtime.h>
#include <hip/hip_bf16.h>
#include <hip/hip_fp16.h>

#define NN 50000
#define NE 800000
#define MP 50048            // NN padded to multiple of 128
#define SCAN_NB 196         // ceil(NN/256)
#define CVT_XB 6256         // MP*128/4/256 blocks for x conversion
#define CVT_WB 448          // 7*16384/256 blocks for w conversion
#define AGG_GRID 2048

typedef __bf16 bf16x8 __attribute__((ext_vector_type(8)));
typedef float f32x4 __attribute__((ext_vector_type(4)));

static __device__ __forceinline__ float b2f(unsigned short u) {
  union { unsigned int i; float f; } v; v.i = ((unsigned int)u) << 16; return v.f;
}
static __device__ __forceinline__ unsigned short f2b(float f) {
  __hip_bfloat16 h = __float2bfloat16(f);
  union { __hip_bfloat16 h; unsigned short u; } v; v.h = h; return v.u;
}
static __device__ __forceinline__ float h2f_bits(unsigned short u) {
  __half h; union { __half h; unsigned short u; } v; v.u = u; h = v.h;
  return __half2float(h);
}
static __device__ __forceinline__ unsigned short f2h_bits(float f) {
  union { __half h; unsigned short u; } v; v.h = __float2half_rn(f); return v.u;
}

static __device__ __forceinline__ int get_src(const int* ei, int f, int i) {
  return f ? ei[2 * i] : ei[i];
}
static __device__ __forceinline__ int get_dst(const int* ei, int f, int i) {
  return f ? ei[2 * (NE + i)] : ei[NE + i];
}

// ---------------- fused: flag detect + dc init + cvt_x + cvt_w ----------------
// dc[i]: high 32 = edge count, low 32 = fixed-point (2^-20) weighted degree
__global__ __launch_bounds__(256) void prep_fused(const int* __restrict__ ei,
    int* flag, unsigned long long* dc,
    const float* __restrict__ x,
    unsigned short* __restrict__ Hh, unsigned short* __restrict__ Hl,
    const float* __restrict__ W1, const float* __restrict__ Wm,
    unsigned short* __restrict__ Wth, unsigned short* __restrict__ Wtl,
    int n, int valid) {
  unsigned int bid = blockIdx.x;
  if (bid < SCAN_NB) {
    int i = bid * 256 + threadIdx.x;
    if (i < n) dc[i] = 1048576ull;   // self-loop weight 1.0, cnt 0
    if (bid == 0 && threadIdx.x < 64) {
      __shared__ int nz;
      if (threadIdx.x == 0) nz = 0;
      __syncthreads();
      if (ei[2 * threadIdx.x + 1] != 0) atomicAdd(&nz, 1);
      __syncthreads();
      if (threadIdx.x == 0) *flag = (nz == 0) ? 1 : 0;   // 1 => int64 layout
    }
  } else if (bid < SCAN_NB + CVT_XB) {
    int b = ((bid - SCAN_NB) * 256 + threadIdx.x) * 4;
    ushort4 oh, ol;
    float v0 = (b + 0 < valid) ? x[b + 0] : 0.f;
    float v1 = (b + 1 < valid) ? x[b + 1] : 0.f;
    float v2 = (b + 2 < valid) ? x[b + 2] : 0.f;
    float v3 = (b + 3 < valid) ? x[b + 3] : 0.f;
    oh.x = f2b(v0); ol.x = f2b(v0 - b2f(oh.x));
    oh.y = f2b(v1); ol.y = f2b(v1 - b2f(oh.y));
    oh.z = f2b(v2); ol.z = f2b(v2 - b2f(oh.z));
    oh.w = f2b(v3); ol.w = f2b(v3 - b2f(oh.w));
    *(ushort4*)(Hh + b) = oh;
    *(ushort4*)(Hl + b) = ol;
  } else {
    int i = (bid - SCAN_NB - CVT_XB) * 256 + threadIdx.x;   // 7*16384
    int l = i >> 14, r = i & 16383;
    int k = r >> 7, nn = r & 127;
    const float* src = (l == 0) ? W1 : (Wm + (size_t)(l - 1) * 16384);
    float v = src[k * 128 + nn];
    unsigned short h = f2b(v);
    int o = l * 16384 + nn * 128 + k;
    Wth[o] = h;
    Wtl[o] = f2b(v - b2f(h));
  }
}

__global__ __launch_bounds__(256) void prep_hist(const int* __restrict__ ei,
    const int* __restrict__ flag, const float* __restrict__ ew,
    unsigned long long* dc, int e) {
  int i = blockIdx.x * 256 + threadIdx.x;
  if (i < e) {
    int f = *flag;
    int d = get_dst(ei, f, i);
    unsigned long long fx = (unsigned long long)(ew[i] * 1048576.0f + 0.5f);
    atomicAdd(&dc[d], (1ull << 32) | fx);
  }
}

// fused: dis/cnt/cursor compute + per-block cnt partial sum
__global__ __launch_bounds__(256) void prep_dis_part(
    const unsigned long long* __restrict__ dc, float* dis, int* cnt,
    int* cursor, int* __restrict__ part, int n) {
  __shared__ int sb[256];
  int t = threadIdx.x, i = blockIdx.x * 256 + t;
  int c = 0;
  if (i < n) {
    unsigned long long v = dc[i];
    float d = (float)(unsigned int)(v & 0xffffffffull) * (1.0f / 1048576.0f);
    dis[i] = (d > 0.f) ? rsqrtf(d) : 0.f;
    c = (int)(v >> 32);
    cnt[i] = c;
    cursor[i] = 0;
  }
  sb[t] = c;
  __syncthreads();
  for (int off = 128; off > 0; off >>= 1) {
    if (t < off) sb[t] += sb[t + off];
    __syncthreads();
  }
  if (t == 0) part[blockIdx.x] = sb[0];
}

// self-contained: each block scans the 196 block-partials in LDS (exclusive
// prefix for its own block), then scans its own 256 cnts. Kills scan_tops.
__global__ __launch_bounds__(256) void scan_apply(const int* __restrict__ cnt,
    const int* __restrict__ part, int* __restrict__ rowstart, int n, int e) {
  __shared__ int sp[256];
  __shared__ int sb[256];
  int t = threadIdx.x, i = blockIdx.x * 256 + t;
  int pv = (t < SCAN_NB) ? part[t] : 0;
  sp[t] = pv;
  int v = (i < n) ? cnt[i] : 0;
  sb[t] = v;
  __syncthreads();
  for (int off = 1; off < 256; off <<= 1) {
    int xa = (t >= off) ? sp[t - off] : 0;
    int xb = (t >= off) ? sb[t - off] : 0;
    __syncthreads();
    sp[t] += xa;
    sb[t] += xb;
    __syncthreads();
  }
  int partoff = (blockIdx.x > 0) ? sp[blockIdx.x - 1] : 0;  // exclusive of own block
  if (i < n) rowstart[i] = partoff + sb[t] - v;
  if (blockIdx.x == 0 && t == 0) rowstart[n] = e;
}

// packed 4B edge record: low16 = src node (N<65536), high16 = fp16 norm bits
__global__ __launch_bounds__(256) void prep_scatter(const int* __restrict__ ei,
    const int* __restrict__ flag, const float* __restrict__ ew,
    const float* __restrict__ dis, const int* __restrict__ rowstart,
    int* __restrict__ cursor, unsigned int* __restrict__ epack, int e) {
  int i = blockIdx.x * 256 + threadIdx.x;
  if (i >= e) return;
  int f = *flag;
  int d = get_dst(ei, f, i);
  int s = get_src(ei, f, i);
  int pos = rowstart[d] + atomicAdd(&cursor[d], 1);
  float nm = dis[s] * ew[i] * dis[d];
  epack[pos] = (unsigned int)s | ((unsigned int)f2h_bits(nm) << 16);
}

// ---------------- MFMA split-bf16 GEMM: XW[MP,128] (fp16) = H @ W ----------------
// 128 rows/block, 32 rows/wave (two 16-row tiles share each B fragment -> 6
// MFMAs per B load). Two-phase LDS-transpose epilogue for coalesced stores.
__global__ __launch_bounds__(256) void gemm_mfma(
    const unsigned short* __restrict__ Hh, const unsigned short* __restrict__ Hl,
    const unsigned short* __restrict__ Bh, const unsigned short* __restrict__ Bl,
    __half* __restrict__ XW) {
  __shared__ float C[64][133];
  int t = threadIdx.x;
  int lane = t & 63, wv = t >> 6;
  int m16 = lane & 15, quad = lane >> 4;
  int rowbase = blockIdx.x * 128;
  int arow0 = rowbase + wv * 32 + m16;
  f32x4 acc0[8], acc1[8];
#pragma unroll
  for (int i = 0; i < 8; ++i) {
    acc0[i] = (f32x4){0.f, 0.f, 0.f, 0.f};
    acc1[i] = (f32x4){0.f, 0.f, 0.f, 0.f};
  }
  const unsigned short* ph0 = Hh + (size_t)arow0 * 128 + quad * 8;
  const unsigned short* pl0 = Hl + (size_t)arow0 * 128 + quad * 8;
#pragma unroll
  for (int kc = 0; kc < 4; ++kc) {
    bf16x8 ah0 = *(const bf16x8*)(ph0 + kc * 32);
    bf16x8 al0 = *(const bf16x8*)(pl0 + kc * 32);
    bf16x8 ah1 = *(const bf16x8*)(ph0 + 16 * 128 + kc * 32);
    bf16x8 al1 = *(const bf16x8*)(pl0 + 16 * 128 + kc * 32);
    int k0 = kc * 32 + quad * 8;
#pragma unroll
    for (int tt = 0; tt < 8; ++tt) {
      int nn = tt * 16 + m16;
      bf16x8 bh = *(const bf16x8*)(Bh + nn * 128 + k0);
      bf16x8 bl = *(const bf16x8*)(Bl + nn * 128 + k0);
      acc0[tt] = __builtin_amdgcn_mfma_f32_16x16x32_bf16(ah0, bh, acc0[tt], 0, 0, 0);
      acc0[tt] = __builtin_amdgcn_mfma_f32_16x16x32_bf16(ah0, bl, acc0[tt], 0, 0, 0);
      acc0[tt] = __builtin_amdgcn_mfma_f32_16x16x32_bf16(al0, bh, acc0[tt], 0, 0, 0);
      acc1[tt] = __builtin_amdgcn_mfma_f32_16x16x32_bf16(ah1, bh, acc1[tt], 0, 0, 0);
      acc1[tt] = __builtin_amdgcn_mfma_f32_16x16x32_bf16(ah1, bl, acc1[tt], 0, 0, 0);
      acc1[tt] = __builtin_amdgcn_mfma_f32_16x16x32_bf16(al1, bh, acc1[tt], 0, 0, 0);
    }
  }
  int rr = t >> 2;               // 0..63
  int cb = (t & 3) * 32;         // col base
  int grow = rowbase + ((rr >> 4) << 5) + (rr & 15);
#pragma unroll
  for (int ph = 0; ph < 2; ++ph) {
    if (ph) __syncthreads();
#pragma unroll
    for (int tt = 0; tt < 8; ++tt)
#pragma unroll
      for (int r = 0; r < 4; ++r)
        C[wv * 16 + quad * 4 + r][tt * 16 + m16] = ph ? acc1[tt][r] : acc0[tt][r];
    __syncthreads();
    const float* crow = &C[rr][cb];
    __half2 o[16];
#pragma unroll
    for (int i = 0; i < 16; ++i) {
      __half2 h;
      h.x = __float2half_rn(crow[2 * i]);
      h.y = __float2half_rn(crow[2 * i + 1]);
      o[i] = h;
    }
    uint4* dst = (uint4*)(XW + (size_t)(grow + ph * 16) * 128 + cb);
    dst[0] = ((const uint4*)o)[0];
    dst[1] = ((const uint4*)o)[1];
    dst[2] = ((const uint4*)o)[2];
    dst[3] = ((const uint4*)o)[3];
  }
}

// ---------------- CSR aggregation + bias + relu -> bf16 hi/lo H ----------------
// grid-stride persistent blocks (low churn); one wave per node; 16-deep
// fully-predicated unroll. launch_bounds(256,8) -> VGPR<=64, 32 waves/CU.
__global__ __launch_bounds__(256, 8) void agg_csr(const __half* __restrict__ XW,
    const int* __restrict__ rowstart, const unsigned int* __restrict__ epack,
    const float* __restrict__ dis, const float* __restrict__ bias,
    unsigned short* __restrict__ Hh, unsigned short* __restrict__ Hl, int n) {
  int l = threadIdx.x & 63;
  int ng = (n + 3) >> 2;
  for (int g = blockIdx.x; g < ng; g += AGG_GRID) {
    int w = g * 4 + (threadIdx.x >> 6);
    if (w >= n) continue;
    float dd = dis[w];
    float d2 = dd * dd;
    __half2 sh = ((const __half2*)(XW + (size_t)w * 128))[l];
    float2 A[8];
    A[0] = make_float2(d2 * __low2float(sh), d2 * __high2float(sh));
#pragma unroll
    for (int i = 1; i < 8; ++i) A[i] = make_float2(0.f, 0.f);
    int p = rowstart[w], p1 = rowstart[w + 1];
    for (; p < p1; p += 16) {
      int idx[16]; unsigned short wtb[16];
#pragma unroll
      for (int i = 0; i < 16; ++i) {
        unsigned int rec = __builtin_nontemporal_load(epack + p + i);  // padded +16
        bool inb = (p + i < p1);
        idx[i] = inb ? (int)(rec & 0xffffu) : w;
        wtb[i] = inb ? (unsigned short)(rec >> 16) : (unsigned short)0;
      }
      __half2 r[16];
#pragma unroll
      for (int i = 0; i < 16; ++i)
        r[i] = ((const __half2*)(XW + (size_t)idx[i] * 128))[l];
#pragma unroll
      for (int i = 0; i < 16; ++i) {
        float wt = h2f_bits(wtb[i]);
        A[i & 7].x = fmaf(wt, __low2float(r[i]), A[i & 7].x);
        A[i & 7].y = fmaf(wt, __high2float(r[i]), A[i & 7].y);
      }
    }
    float2 b = ((const float2*)bias)[l];
    float vx = fmaxf(A[0].x + A[1].x + A[2].x + A[3].x + A[4].x + A[5].x + A[6].x + A[7].x + b.x, 0.f);
    float vy = fmaxf(A[0].y + A[1].y + A[2].y + A[3].y + A[4].y + A[5].y + A[6].y + A[7].y + b.y, 0.f);
    ushort2 oh, ol;
    oh.x = f2b(vx); ol.x = f2b(vx - b2f(oh.x));
    oh.y = f2b(vy); ol.y = f2b(vy - b2f(oh.y));
    ((ushort2*)(Hh + (size_t)w * 128))[l] = oh;
    ((ushort2*)(Hl + (size_t)w * 128))[l] = ol;
  }
}

// ---------------- final layer ----------------
__global__ __launch_bounds__(256) void gemm_w8(const unsigned short* __restrict__ Hh,
    const unsigned short* __restrict__ Hl, const float* __restrict__ W8,
    float* __restrict__ XW2, int n) {
  __shared__ float w[256];
  int t = threadIdx.x;
  w[t] = W8[t];
  __syncthreads();
  int r = blockIdx.x * 256 + t;
  if (r >= n) return;
  const unsigned short* hh = Hh + (size_t)r * 128;
  const unsigned short* hl = Hl + (size_t)r * 128;
  float a0 = 0.f, a1 = 0.f;
#pragma unroll
  for (int k = 0; k < 128; k += 4) {
    ushort4 uh = *(const ushort4*)(hh + k);
    ushort4 ul = *(const ushort4*)(hl + k);
    float h0 = b2f(uh.x) + b2f(ul.x);
    float h1 = b2f(uh.y) + b2f(ul.y);
    float h2 = b2f(uh.z) + b2f(ul.z);
    float h3 = b2f(uh.w) + b2f(ul.w);
    a0 += h0 * w[2 * k + 0] + h1 * w[2 * k + 2] + h2 * w[2 * k + 4] + h3 * w[2 * k + 6];
    a1 += h0 * w[2 * k + 1] + h1 * w[2 * k + 3] + h2 * w[2 * k + 5] + h3 * w[2 * k + 7];
  }
  XW2[r * 2 + 0] = a0;
  XW2[r * 2 + 1] = a1;
}

__global__ __launch_bounds__(256) void agg_final(const float* __restrict__ XW2,
    const int* __restrict__ rowstart, const unsigned int* __restrict__ epack,
    const float* __restrict__ dis, const float* __restrict__ b8,
    float* __restrict__ out, int n) {
  int i = blockIdx.x * 256 + threadIdx.x;
  if (i >= n) return;
  float d = dis[i], d2 = d * d;
  float a0 = d2 * XW2[i * 2 + 0];
  float a1 = d2 * XW2[i * 2 + 1];
  int p1 = rowstart[i + 1];
  for (int p = rowstart[i]; p < p1; ++p) {
    unsigned int rec = epack[p];
    int s = (int)(rec & 0xffffu);
    float wt = h2f_bits((unsigned short)(rec >> 16));
    a0 = fmaf(wt, XW2[s * 2 + 0], a0);
    a1 = fmaf(wt, XW2[s * 2 + 1], a1);
  }
  out[i * 2 + 0] = a0 + b8[0];
  out[i * 2 + 1] = a1 + b8[1];
}

// ---------------- launcher ----------------
static inline char* alignp(char* p) {
  return (char*)(((uintptr_t)p + 255) & ~(uintptr_t)255);
}

extern "C" void kernel_launch(void* const* d_in, const int* in_sizes, int n_in,
                              void* d_out, int out_size, void* d_ws, size_t ws_size,
                              hipStream_t stream) {
  (void)in_sizes; (void)n_in; (void)out_size; (void)ws_size;
  const int n = NN, e = NE;
  const float* x  = (const float*)d_in[0];
  const int*   ei = (const int*)d_in[1];
  const float* ea = (const float*)d_in[2];
  const float* W1 = (const float*)d_in[3];
  const float* b1 = (const float*)d_in[4];
  const float* Wm = (const float*)d_in[5];
  const float* bm = (const float*)d_in[6];
  const float* W8 = (const float*)d_in[7];
  const float* b8 = (const float*)d_in[8];
  float* out = (float*)d_out;

  char* w = (char*)d_ws;
  int*   flag   = (int*)w;            w = alignp(w + 4);
  int*   part   = (int*)w;            w = alignp(w + SCAN_NB * 4);
  unsigned long long* dc = (unsigned long long*)w; w = alignp(w + (size_t)n * 8);
  float* dis    = (float*)w;          w = alignp(w + (size_t)n * 4);
  int*   cnt    = (int*)w;            w = alignp(w + (size_t)n * 4);
  int*   cursor = (int*)w;            w = alignp(w + (size_t)n * 4);
  int*   rowst  = (int*)w;            w = alignp(w + (size_t)(n + 1) * 4);
  unsigned int* epack = (unsigned int*)w;    w = alignp(w + (size_t)(e + 16) * 4);
  unsigned short* Hh  = (unsigned short*)w;  w = alignp(w + (size_t)MP * 128 * 2);
  unsigned short* Hl  = (unsigned short*)w;  w = alignp(w + (size_t)MP * 128 * 2);
  unsigned short* Wth = (unsigned short*)w;  w = alignp(w + (size_t)7 * 16384 * 2);
  unsigned short* Wtl = (unsigned short*)w;  w = alignp(w + (size_t)7 * 16384 * 2);
  __half* XW  = (__half*)w;           w = alignp(w + (size_t)MP * 128 * 2);
  float* XW2  = (float*)w;            w = alignp(w + (size_t)MP * 2 * 4);

  const int GN = (n + 255) / 256;
  const int GE = (e + 255) / 256;

  prep_fused<<<SCAN_NB + CVT_XB + CVT_WB, 256, 0, stream>>>(
      ei, flag, dc, x, Hh, Hl, W1, Wm, Wth, Wtl, n, n * 128);
  prep_hist<<<GE, 256, 0, stream>>>(ei, flag, ea, dc, e);
  prep_dis_part<<<SCAN_NB, 256, 0, stream>>>(dc, dis, cnt, cursor, part, n);
  scan_apply<<<SCAN_NB, 256, 0, stream>>>(cnt, part, rowst, n, e);
  prep_scatter<<<GE, 256, 0, stream>>>(ei, flag, ea, dis, rowst, cursor, epack, e);

  for (int l = 0; l < 7; ++l) {
    const unsigned short* Bh = Wth + (size_t)l * 16384;
    const unsigned short* Bl = Wtl + (size_t)l * 16384;
    const float* bl = (l == 0) ? b1 : bm + (size_t)(l - 1) * 128;
    gemm_mfma<<<MP / 128, 256, 0, stream>>>(Hh, Hl, Bh, Bl, XW);
    agg_csr<<<AGG_GRID, 256, 0, stream>>>(XW, rowst, epack, dis, bl, Hh, Hl, n);
  }
  gemm_w8<<<GN, 256, 0, stream>>>(Hh, Hl, W8, XW2, n);
  agg_final<<<GN, 256, 0, stream>>>(XW2, rowst, epack, dis, b8, out, n);
}

// Round 10
// 596.485 us; speedup vs baseline: 1.1518x; 1.1518x over previous
//
#include <hip/hip_runtime.h>
#include <hip/hip_bf16.h>
#include <hip/hip_fp16.h>

#define NN 50000
#define NE 800000
#define MP 50048            // NN padded to multiple of 128
#define SCAN_NB 196         // ceil(NN/256)
#define CVT_XB 6256         // MP*128/4/256 blocks for x conversion
#define CVT_WB 448          // 7*16384/256 blocks for w conversion

typedef __bf16 bf16x8 __attribute__((ext_vector_type(8)));
typedef float f32x4 __attribute__((ext_vector_type(4)));

static __device__ __forceinline__ float b2f(unsigned short u) {
  union { unsigned int i; float f; } v; v.i = ((unsigned int)u) << 16; return v.f;
}
static __device__ __forceinline__ unsigned short f2b(float f) {
  __hip_bfloat16 h = __float2bfloat16(f);
  union { __hip_bfloat16 h; unsigned short u; } v; v.h = h; return v.u;
}
static __device__ __forceinline__ float h2f_bits(unsigned short u) {
  __half h; union { __half h; unsigned short u; } v; v.u = u; h = v.h;
  return __half2float(h);
}
static __device__ __forceinline__ unsigned short f2h_bits(float f) {
  union { __half h; unsigned short u; } v; v.h = __float2half_rn(f); return v.u;
}

static __device__ __forceinline__ int get_src(const int* ei, int f, int i) {
  return f ? ei[2 * i] : ei[i];
}
static __device__ __forceinline__ int get_dst(const int* ei, int f, int i) {
  return f ? ei[2 * (NE + i)] : ei[NE + i];
}

// ---------------- fused: flag detect + dc init + cvt_x + cvt_w ----------------
// dc[i]: high 32 = edge count, low 32 = fixed-point (2^-20) weighted degree
__global__ __launch_bounds__(256) void prep_fused(const int* __restrict__ ei,
    int* flag, unsigned long long* dc,
    const float* __restrict__ x,
    unsigned short* __restrict__ Hh, unsigned short* __restrict__ Hl,
    const float* __restrict__ W1, const float* __restrict__ Wm,
    unsigned short* __restrict__ Wth, unsigned short* __restrict__ Wtl,
    int n, int valid) {
  unsigned int bid = blockIdx.x;
  if (bid < SCAN_NB) {
    int i = bid * 256 + threadIdx.x;
    if (i < n) dc[i] = 1048576ull;   // self-loop weight 1.0, cnt 0
    if (bid == 0 && threadIdx.x < 64) {
      __shared__ int nz;
      if (threadIdx.x == 0) nz = 0;
      __syncthreads();
      if (ei[2 * threadIdx.x + 1] != 0) atomicAdd(&nz, 1);
      __syncthreads();
      if (threadIdx.x == 0) *flag = (nz == 0) ? 1 : 0;   // 1 => int64 layout
    }
  } else if (bid < SCAN_NB + CVT_XB) {
    int b = ((bid - SCAN_NB) * 256 + threadIdx.x) * 4;
    ushort4 oh, ol;
    float v0 = (b + 0 < valid) ? x[b + 0] : 0.f;
    float v1 = (b + 1 < valid) ? x[b + 1] : 0.f;
    float v2 = (b + 2 < valid) ? x[b + 2] : 0.f;
    float v3 = (b + 3 < valid) ? x[b + 3] : 0.f;
    oh.x = f2b(v0); ol.x = f2b(v0 - b2f(oh.x));
    oh.y = f2b(v1); ol.y = f2b(v1 - b2f(oh.y));
    oh.z = f2b(v2); ol.z = f2b(v2 - b2f(oh.z));
    oh.w = f2b(v3); ol.w = f2b(v3 - b2f(oh.w));
    *(ushort4*)(Hh + b) = oh;
    *(ushort4*)(Hl + b) = ol;
  } else {
    int i = (bid - SCAN_NB - CVT_XB) * 256 + threadIdx.x;   // 7*16384
    int l = i >> 14, r = i & 16383;
    int k = r >> 7, nn = r & 127;
    const float* src = (l == 0) ? W1 : (Wm + (size_t)(l - 1) * 16384);
    float v = src[k * 128 + nn];
    unsigned short h = f2b(v);
    int o = l * 16384 + nn * 128 + k;
    Wth[o] = h;
    Wtl[o] = f2b(v - b2f(h));
  }
}

__global__ __launch_bounds__(256) void prep_hist(const int* __restrict__ ei,
    const int* __restrict__ flag, const float* __restrict__ ew,
    unsigned long long* dc, int e) {
  int i = blockIdx.x * 256 + threadIdx.x;
  if (i < e) {
    int f = *flag;
    int d = get_dst(ei, f, i);
    unsigned long long fx = (unsigned long long)(ew[i] * 1048576.0f + 0.5f);
    atomicAdd(&dc[d], (1ull << 32) | fx);
  }
}

// fused: dis/cnt/cursor compute + per-block cnt partial sum
__global__ __launch_bounds__(256) void prep_dis_part(
    const unsigned long long* __restrict__ dc, float* dis, int* cnt,
    int* cursor, int* __restrict__ part, int n) {
  __shared__ int sb[256];
  int t = threadIdx.x, i = blockIdx.x * 256 + t;
  int c = 0;
  if (i < n) {
    unsigned long long v = dc[i];
    float d = (float)(unsigned int)(v & 0xffffffffull) * (1.0f / 1048576.0f);
    dis[i] = (d > 0.f) ? rsqrtf(d) : 0.f;
    c = (int)(v >> 32);
    cnt[i] = c;
    cursor[i] = 0;
  }
  sb[t] = c;
  __syncthreads();
  for (int off = 128; off > 0; off >>= 1) {
    if (t < off) sb[t] += sb[t + off];
    __syncthreads();
  }
  if (t == 0) part[blockIdx.x] = sb[0];
}

// self-contained: each block scans the 196 block-partials in LDS (exclusive
// prefix for its own block), then scans its own 256 cnts.
__global__ __launch_bounds__(256) void scan_apply(const int* __restrict__ cnt,
    const int* __restrict__ part, int* __restrict__ rowstart, int n, int e) {
  __shared__ int sp[256];
  __shared__ int sb[256];
  int t = threadIdx.x, i = blockIdx.x * 256 + t;
  int pv = (t < SCAN_NB) ? part[t] : 0;
  sp[t] = pv;
  int v = (i < n) ? cnt[i] : 0;
  sb[t] = v;
  __syncthreads();
  for (int off = 1; off < 256; off <<= 1) {
    int xa = (t >= off) ? sp[t - off] : 0;
    int xb = (t >= off) ? sb[t - off] : 0;
    __syncthreads();
    sp[t] += xa;
    sb[t] += xb;
    __syncthreads();
  }
  int partoff = (blockIdx.x > 0) ? sp[blockIdx.x - 1] : 0;  // exclusive of own block
  if (i < n) rowstart[i] = partoff + sb[t] - v;
  if (blockIdx.x == 0 && t == 0) rowstart[n] = e;
}

// packed 4B edge record: low16 = src node (N<65536), high16 = fp16 norm bits
__global__ __launch_bounds__(256) void prep_scatter(const int* __restrict__ ei,
    const int* __restrict__ flag, const float* __restrict__ ew,
    const float* __restrict__ dis, const int* __restrict__ rowstart,
    int* __restrict__ cursor, unsigned int* __restrict__ epack, int e) {
  int i = blockIdx.x * 256 + threadIdx.x;
  if (i >= e) return;
  int f = *flag;
  int d = get_dst(ei, f, i);
  int s = get_src(ei, f, i);
  int pos = rowstart[d] + atomicAdd(&cursor[d], 1);
  float nm = dis[s] * ew[i] * dis[d];
  epack[pos] = (unsigned int)s | ((unsigned int)f2h_bits(nm) << 16);
}

// ---------------- MFMA split-bf16 GEMM: XW[MP,128] (fp16) = H @ W ----------------
// 128 rows/block, 32 rows/wave (two 16-row tiles share each B fragment -> 6
// MFMAs per B load). Two-phase LDS-transpose epilogue for coalesced stores.
__global__ __launch_bounds__(256) void gemm_mfma(
    const unsigned short* __restrict__ Hh, const unsigned short* __restrict__ Hl,
    const unsigned short* __restrict__ Bh, const unsigned short* __restrict__ Bl,
    __half* __restrict__ XW) {
  __shared__ float C[64][133];
  int t = threadIdx.x;
  int lane = t & 63, wv = t >> 6;
  int m16 = lane & 15, quad = lane >> 4;
  int rowbase = blockIdx.x * 128;
  int arow0 = rowbase + wv * 32 + m16;
  f32x4 acc0[8], acc1[8];
#pragma unroll
  for (int i = 0; i < 8; ++i) {
    acc0[i] = (f32x4){0.f, 0.f, 0.f, 0.f};
    acc1[i] = (f32x4){0.f, 0.f, 0.f, 0.f};
  }
  const unsigned short* ph0 = Hh + (size_t)arow0 * 128 + quad * 8;
  const unsigned short* pl0 = Hl + (size_t)arow0 * 128 + quad * 8;
#pragma unroll
  for (int kc = 0; kc < 4; ++kc) {
    bf16x8 ah0 = *(const bf16x8*)(ph0 + kc * 32);
    bf16x8 al0 = *(const bf16x8*)(pl0 + kc * 32);
    bf16x8 ah1 = *(const bf16x8*)(ph0 + 16 * 128 + kc * 32);
    bf16x8 al1 = *(const bf16x8*)(pl0 + 16 * 128 + kc * 32);
    int k0 = kc * 32 + quad * 8;
#pragma unroll
    for (int tt = 0; tt < 8; ++tt) {
      int nn = tt * 16 + m16;
      bf16x8 bh = *(const bf16x8*)(Bh + nn * 128 + k0);
      bf16x8 bl = *(const bf16x8*)(Bl + nn * 128 + k0);
      acc0[tt] = __builtin_amdgcn_mfma_f32_16x16x32_bf16(ah0, bh, acc0[tt], 0, 0, 0);
      acc0[tt] = __builtin_amdgcn_mfma_f32_16x16x32_bf16(ah0, bl, acc0[tt], 0, 0, 0);
      acc0[tt] = __builtin_amdgcn_mfma_f32_16x16x32_bf16(al0, bh, acc0[tt], 0, 0, 0);
      acc1[tt] = __builtin_amdgcn_mfma_f32_16x16x32_bf16(ah1, bh, acc1[tt], 0, 0, 0);
      acc1[tt] = __builtin_amdgcn_mfma_f32_16x16x32_bf16(ah1, bl, acc1[tt], 0, 0, 0);
      acc1[tt] = __builtin_amdgcn_mfma_f32_16x16x32_bf16(al1, bh, acc1[tt], 0, 0, 0);
    }
  }
  int rr = t >> 2;               // 0..63
  int cb = (t & 3) * 32;         // col base
  int grow = rowbase + ((rr >> 4) << 5) + (rr & 15);
#pragma unroll
  for (int ph = 0; ph < 2; ++ph) {
    if (ph) __syncthreads();
#pragma unroll
    for (int tt = 0; tt < 8; ++tt)
#pragma unroll
      for (int r = 0; r < 4; ++r)
        C[wv * 16 + quad * 4 + r][tt * 16 + m16] = ph ? acc1[tt][r] : acc0[tt][r];
    __syncthreads();
    const float* crow = &C[rr][cb];
    __half2 o[16];
#pragma unroll
    for (int i = 0; i < 16; ++i) {
      __half2 h;
      h.x = __float2half_rn(crow[2 * i]);
      h.y = __float2half_rn(crow[2 * i + 1]);
      o[i] = h;
    }
    uint4* dst = (uint4*)(XW + (size_t)(grow + ph * 16) * 128 + cb);
    dst[0] = ((const uint4*)o)[0];
    dst[1] = ((const uint4*)o)[1];
    dst[2] = ((const uint4*)o)[2];
    dst[3] = ((const uint4*)o)[3];
  }
}

// ---------------- CSR aggregation + bias + relu -> bf16 hi/lo H ----------------
// one wave per node; 16-deep fully-predicated unroll (no serial tail).
// NOTE (r9 lesson): no min-waves launch bound — capping VGPR at 32 serializes
// the 16-gather pipeline (measured 49.6 vs 44 µs); plain loads, no nt hints.
__global__ __launch_bounds__(256) void agg_csr(const __half* __restrict__ XW,
    const int* __restrict__ rowstart, const unsigned int* __restrict__ epack,
    const float* __restrict__ dis, const float* __restrict__ bias,
    unsigned short* __restrict__ Hh, unsigned short* __restrict__ Hl, int n) {
  int w = (blockIdx.x * 256 + threadIdx.x) >> 6;
  int l = threadIdx.x & 63;
  if (w >= n) return;
  float dd = dis[w];
  float d2 = dd * dd;
  __half2 sh = ((const __half2*)(XW + (size_t)w * 128))[l];
  float2 A[8];
  A[0] = make_float2(d2 * __low2float(sh), d2 * __high2float(sh));
#pragma unroll
  for (int i = 1; i < 8; ++i) A[i] = make_float2(0.f, 0.f);
  int p = rowstart[w], p1 = rowstart[w + 1];
  for (; p < p1; p += 16) {
    int idx[16]; unsigned short wtb[16];
#pragma unroll
    for (int i = 0; i < 16; ++i) {
      unsigned int rec = epack[p + i];     // epack padded +16: safe overread
      bool inb = (p + i < p1);
      idx[i] = inb ? (int)(rec & 0xffffu) : w;
      wtb[i] = inb ? (unsigned short)(rec >> 16) : (unsigned short)0;
    }
    __half2 r[16];
#pragma unroll
    for (int i = 0; i < 16; ++i)
      r[i] = ((const __half2*)(XW + (size_t)idx[i] * 128))[l];
#pragma unroll
    for (int i = 0; i < 16; ++i) {
      float wt = h2f_bits(wtb[i]);
      A[i & 7].x = fmaf(wt, __low2float(r[i]), A[i & 7].x);
      A[i & 7].y = fmaf(wt, __high2float(r[i]), A[i & 7].y);
    }
  }
  float2 b = ((const float2*)bias)[l];
  float vx = fmaxf(A[0].x + A[1].x + A[2].x + A[3].x + A[4].x + A[5].x + A[6].x + A[7].x + b.x, 0.f);
  float vy = fmaxf(A[0].y + A[1].y + A[2].y + A[3].y + A[4].y + A[5].y + A[6].y + A[7].y + b.y, 0.f);
  ushort2 oh, ol;
  oh.x = f2b(vx); ol.x = f2b(vx - b2f(oh.x));
  oh.y = f2b(vy); ol.y = f2b(vy - b2f(oh.y));
  ((ushort2*)(Hh + (size_t)w * 128))[l] = oh;
  ((ushort2*)(Hl + (size_t)w * 128))[l] = ol;
}

// ---------------- final layer ----------------
__global__ __launch_bounds__(256) void gemm_w8(const unsigned short* __restrict__ Hh,
    const unsigned short* __restrict__ Hl, const float* __restrict__ W8,
    float* __restrict__ XW2, int n) {
  __shared__ float w[256];
  int t = threadIdx.x;
  w[t] = W8[t];
  __syncthreads();
  int r = blockIdx.x * 256 + t;
  if (r >= n) return;
  const unsigned short* hh = Hh + (size_t)r * 128;
  const unsigned short* hl = Hl + (size_t)r * 128;
  float a0 = 0.f, a1 = 0.f;
#pragma unroll
  for (int k = 0; k < 128; k += 4) {
    ushort4 uh = *(const ushort4*)(hh + k);
    ushort4 ul = *(const ushort4*)(hl + k);
    float h0 = b2f(uh.x) + b2f(ul.x);
    float h1 = b2f(uh.y) + b2f(ul.y);
    float h2 = b2f(uh.z) + b2f(ul.z);
    float h3 = b2f(uh.w) + b2f(ul.w);
    a0 += h0 * w[2 * k + 0] + h1 * w[2 * k + 2] + h2 * w[2 * k + 4] + h3 * w[2 * k + 6];
    a1 += h0 * w[2 * k + 1] + h1 * w[2 * k + 3] + h2 * w[2 * k + 5] + h3 * w[2 * k + 7];
  }
  XW2[r * 2 + 0] = a0;
  XW2[r * 2 + 1] = a1;
}

__global__ __launch_bounds__(256) void agg_final(const float* __restrict__ XW2,
    const int* __restrict__ rowstart, const unsigned int* __restrict__ epack,
    const float* __restrict__ dis, const float* __restrict__ b8,
    float* __restrict__ out, int n) {
  int i = blockIdx.x * 256 + threadIdx.x;
  if (i >= n) return;
  float d = dis[i], d2 = d * d;
  float a0 = d2 * XW2[i * 2 + 0];
  float a1 = d2 * XW2[i * 2 + 1];
  int p1 = rowstart[i + 1];
  for (int p = rowstart[i]; p < p1; ++p) {
    unsigned int rec = epack[p];
    int s = (int)(rec & 0xffffu);
    float wt = h2f_bits((unsigned short)(rec >> 16));
    a0 = fmaf(wt, XW2[s * 2 + 0], a0);
    a1 = fmaf(wt, XW2[s * 2 + 1], a1);
  }
  out[i * 2 + 0] = a0 + b8[0];
  out[i * 2 + 1] = a1 + b8[1];
}

// ---------------- launcher ----------------
static inline char* alignp(char* p) {
  return (char*)(((uintptr_t)p + 255) & ~(uintptr_t)255);
}

extern "C" void kernel_launch(void* const* d_in, const int* in_sizes, int n_in,
                              void* d_out, int out_size, void* d_ws, size_t ws_size,
                              hipStream_t stream) {
  (void)in_sizes; (void)n_in; (void)out_size; (void)ws_size;
  const int n = NN, e = NE;
  const float* x  = (const float*)d_in[0];
  const int*   ei = (const int*)d_in[1];
  const float* ea = (const float*)d_in[2];
  const float* W1 = (const float*)d_in[3];
  const float* b1 = (const float*)d_in[4];
  const float* Wm = (const float*)d_in[5];
  const float* bm = (const float*)d_in[6];
  const float* W8 = (const float*)d_in[7];
  const float* b8 = (const float*)d_in[8];
  float* out = (float*)d_out;

  char* w = (char*)d_ws;
  int*   flag   = (int*)w;            w = alignp(w + 4);
  int*   part   = (int*)w;            w = alignp(w + SCAN_NB * 4);
  unsigned long long* dc = (unsigned long long*)w; w = alignp(w + (size_t)n * 8);
  float* dis    = (float*)w;          w = alignp(w + (size_t)n * 4);
  int*   cnt    = (int*)w;            w = alignp(w + (size_t)n * 4);
  int*   cursor = (int*)w;            w = alignp(w + (size_t)n * 4);
  int*   rowst  = (int*)w;            w = alignp(w + (size_t)(n + 1) * 4);
  unsigned int* epack = (unsigned int*)w;    w = alignp(w + (size_t)(e + 16) * 4);
  unsigned short* Hh  = (unsigned short*)w;  w = alignp(w + (size_t)MP * 128 * 2);
  unsigned short* Hl  = (unsigned short*)w;  w = alignp(w + (size_t)MP * 128 * 2);
  unsigned short* Wth = (unsigned short*)w;  w = alignp(w + (size_t)7 * 16384 * 2);
  unsigned short* Wtl = (unsigned short*)w;  w = alignp(w + (size_t)7 * 16384 * 2);
  __half* XW  = (__half*)w;           w = alignp(w + (size_t)MP * 128 * 2);
  float* XW2  = (float*)w;            w = alignp(w + (size_t)MP * 2 * 4);

  const int GN = (n + 255) / 256;
  const int GE = (e + 255) / 256;

  prep_fused<<<SCAN_NB + CVT_XB + CVT_WB, 256, 0, stream>>>(
      ei, flag, dc, x, Hh, Hl, W1, Wm, Wth, Wtl, n, n * 128);
  prep_hist<<<GE, 256, 0, stream>>>(ei, flag, ea, dc, e);
  prep_dis_part<<<SCAN_NB, 256, 0, stream>>>(dc, dis, cnt, cursor, part, n);
  scan_apply<<<SCAN_NB, 256, 0, stream>>>(cnt, part, rowst, n, e);
  prep_scatter<<<GE, 256, 0, stream>>>(ei, flag, ea, dis, rowst, cursor, epack, e);

  for (int l = 0; l < 7; ++l) {
    const unsigned short* Bh = Wth + (size_t)l * 16384;
    const unsigned short* Bl = Wtl + (size_t)l * 16384;
    const float* bl = (l == 0) ? b1 : bm + (size_t)(l - 1) * 128;
    gemm_mfma<<<MP / 128, 256, 0, stream>>>(Hh, Hl, Bh, Bl, XW);
    agg_csr<<<(n * 64 + 255) / 256, 256, 0, stream>>>(XW, rowst, epack, dis, bl, Hh, Hl, n);
  }
  gemm_w8<<<GN, 256, 0, stream>>>(Hh, Hl, W8, XW2, n);
  agg_final<<<GN, 256, 0, stream>>>(XW2, rowst, epack, dis, b8, out, n);
}

// Round 11
// 553.076 us; speedup vs baseline: 1.2422x; 1.0785x over previous
//
#include <hip/hip_runtime.h>
#include <hip/hip_bf16.h>
#include <hip/hip_fp16.h>

#define NN 50000
#define NE 800000
#define MP 50048            // NN padded to multiple of 128
#define SCAN_NB 196         // ceil(NN/256)
#define CVT_XB 6256         // MP*128/4/256 blocks for x conversion
#define CVT_WB 448          // 7*16384/256 blocks for w conversion

typedef __bf16 bf16x8 __attribute__((ext_vector_type(8)));
typedef float f32x4 __attribute__((ext_vector_type(4)));

static __device__ __forceinline__ float b2f(unsigned short u) {
  union { unsigned int i; float f; } v; v.i = ((unsigned int)u) << 16; return v.f;
}
static __device__ __forceinline__ unsigned short f2b(float f) {
  __hip_bfloat16 h = __float2bfloat16(f);
  union { __hip_bfloat16 h; unsigned short u; } v; v.h = h; return v.u;
}
static __device__ __forceinline__ float h2f_bits(unsigned short u) {
  __half h; union { __half h; unsigned short u; } v; v.u = u; h = v.h;
  return __half2float(h);
}
static __device__ __forceinline__ unsigned short f2h_bits(float f) {
  union { __half h; unsigned short u; } v; v.h = __float2half_rn(f); return v.u;
}

static __device__ __forceinline__ int get_src(const int* ei, int f, int i) {
  return f ? ei[2 * i] : ei[i];
}
static __device__ __forceinline__ int get_dst(const int* ei, int f, int i) {
  return f ? ei[2 * (NE + i)] : ei[NE + i];
}

// ---------------- fused: flag detect + dc init + cvt_x + cvt_w ----------------
// dc[i]: high 32 = edge count, low 32 = fixed-point (2^-20) weighted degree
__global__ __launch_bounds__(256) void prep_fused(const int* __restrict__ ei,
    int* flag, unsigned long long* dc,
    const float* __restrict__ x,
    unsigned short* __restrict__ Hh, unsigned short* __restrict__ Hl,
    const float* __restrict__ W1, const float* __restrict__ Wm,
    unsigned short* __restrict__ Wth, unsigned short* __restrict__ Wtl,
    int n, int valid) {
  unsigned int bid = blockIdx.x;
  if (bid < SCAN_NB) {
    int i = bid * 256 + threadIdx.x;
    if (i < n) dc[i] = 1048576ull;   // self-loop weight 1.0, cnt 0
    if (bid == 0 && threadIdx.x < 64) {
      __shared__ int nz;
      if (threadIdx.x == 0) nz = 0;
      __syncthreads();
      if (ei[2 * threadIdx.x + 1] != 0) atomicAdd(&nz, 1);
      __syncthreads();
      if (threadIdx.x == 0) *flag = (nz == 0) ? 1 : 0;   // 1 => int64 layout
    }
  } else if (bid < SCAN_NB + CVT_XB) {
    int b = ((bid - SCAN_NB) * 256 + threadIdx.x) * 4;
    ushort4 oh, ol;
    float v0 = (b + 0 < valid) ? x[b + 0] : 0.f;
    float v1 = (b + 1 < valid) ? x[b + 1] : 0.f;
    float v2 = (b + 2 < valid) ? x[b + 2] : 0.f;
    float v3 = (b + 3 < valid) ? x[b + 3] : 0.f;
    oh.x = f2b(v0); ol.x = f2b(v0 - b2f(oh.x));
    oh.y = f2b(v1); ol.y = f2b(v1 - b2f(oh.y));
    oh.z = f2b(v2); ol.z = f2b(v2 - b2f(oh.z));
    oh.w = f2b(v3); ol.w = f2b(v3 - b2f(oh.w));
    *(ushort4*)(Hh + b) = oh;
    *(ushort4*)(Hl + b) = ol;
  } else {
    int i = (bid - SCAN_NB - CVT_XB) * 256 + threadIdx.x;   // 7*16384
    int l = i >> 14, r = i & 16383;
    int k = r >> 7, nn = r & 127;
    const float* src = (l == 0) ? W1 : (Wm + (size_t)(l - 1) * 16384);
    float v = src[k * 128 + nn];
    unsigned short h = f2b(v);
    int o = l * 16384 + nn * 128 + k;
    Wth[o] = h;
    Wtl[o] = f2b(v - b2f(h));
  }
}

// histogram; atomic's return value gives each edge its per-node ordinal (free)
__global__ __launch_bounds__(256) void prep_hist(const int* __restrict__ ei,
    const int* __restrict__ flag, const float* __restrict__ ew,
    unsigned long long* dc, unsigned short* __restrict__ ord, int e) {
  int i = blockIdx.x * 256 + threadIdx.x;
  if (i < e) {
    int f = *flag;
    int d = get_dst(ei, f, i);
    unsigned long long fx = (unsigned long long)(ew[i] * 1048576.0f + 0.5f);
    unsigned long long old = atomicAdd(&dc[d], (1ull << 32) | fx);
    ord[i] = (unsigned short)(old >> 32);
  }
}

// fused: dis/cnt compute + per-block cnt partial sum
__global__ __launch_bounds__(256) void prep_dis_part(
    const unsigned long long* __restrict__ dc, float* dis, int* cnt,
    int* __restrict__ part, int n) {
  __shared__ int sb[256];
  int t = threadIdx.x, i = blockIdx.x * 256 + t;
  int c = 0;
  if (i < n) {
    unsigned long long v = dc[i];
    float d = (float)(unsigned int)(v & 0xffffffffull) * (1.0f / 1048576.0f);
    dis[i] = (d > 0.f) ? rsqrtf(d) : 0.f;
    c = (int)(v >> 32);
    cnt[i] = c;
  }
  sb[t] = c;
  __syncthreads();
  for (int off = 128; off > 0; off >>= 1) {
    if (t < off) sb[t] += sb[t + off];
    __syncthreads();
  }
  if (t == 0) part[blockIdx.x] = sb[0];
}

// self-contained: each block scans the 196 block-partials in LDS (exclusive
// prefix for its own block), then scans its own 256 cnts.
__global__ __launch_bounds__(256) void scan_apply(const int* __restrict__ cnt,
    const int* __restrict__ part, int* __restrict__ rowstart, int n, int e) {
  __shared__ int sp[256];
  __shared__ int sb[256];
  int t = threadIdx.x, i = blockIdx.x * 256 + t;
  int pv = (t < SCAN_NB) ? part[t] : 0;
  sp[t] = pv;
  int v = (i < n) ? cnt[i] : 0;
  sb[t] = v;
  __syncthreads();
  for (int off = 1; off < 256; off <<= 1) {
    int xa = (t >= off) ? sp[t - off] : 0;
    int xb = (t >= off) ? sb[t - off] : 0;
    __syncthreads();
    sp[t] += xa;
    sb[t] += xb;
    __syncthreads();
  }
  int partoff = (blockIdx.x > 0) ? sp[blockIdx.x - 1] : 0;  // exclusive of own block
  if (i < n) rowstart[i] = partoff + sb[t] - v;
  if (blockIdx.x == 0 && t == 0) rowstart[n] = e;
}

// packed 4B edge record: low16 = src node (N<65536), high16 = fp16 norm bits
// pos from rowstart + precomputed ordinal — no atomics here.
__global__ __launch_bounds__(256) void prep_scatter(const int* __restrict__ ei,
    const int* __restrict__ flag, const float* __restrict__ ew,
    const float* __restrict__ dis, const int* __restrict__ rowstart,
    const unsigned short* __restrict__ ord, unsigned int* __restrict__ epack, int e) {
  int i = blockIdx.x * 256 + threadIdx.x;
  if (i >= e) return;
  int f = *flag;
  int d = get_dst(ei, f, i);
  int s = get_src(ei, f, i);
  int pos = rowstart[d] + (int)ord[i];
  float nm = dis[s] * ew[i] * dis[d];
  epack[pos] = (unsigned int)s | ((unsigned int)f2h_bits(nm) << 16);
}

// ---------------- MFMA split-bf16 GEMM: XW[MP,128] (fp16) = H @ W ----------------
__global__ __launch_bounds__(256) void gemm_mfma(
    const unsigned short* __restrict__ Hh, const unsigned short* __restrict__ Hl,
    const unsigned short* __restrict__ Bh, const unsigned short* __restrict__ Bl,
    __half* __restrict__ XW) {
  __shared__ float C[64][133];
  int t = threadIdx.x;
  int lane = t & 63, wv = t >> 6;
  int m16 = lane & 15, quad = lane >> 4;
  int rowbase = blockIdx.x * 128;
  int arow0 = rowbase + wv * 32 + m16;
  f32x4 acc0[8], acc1[8];
#pragma unroll
  for (int i = 0; i < 8; ++i) {
    acc0[i] = (f32x4){0.f, 0.f, 0.f, 0.f};
    acc1[i] = (f32x4){0.f, 0.f, 0.f, 0.f};
  }
  const unsigned short* ph0 = Hh + (size_t)arow0 * 128 + quad * 8;
  const unsigned short* pl0 = Hl + (size_t)arow0 * 128 + quad * 8;
#pragma unroll
  for (int kc = 0; kc < 4; ++kc) {
    bf16x8 ah0 = *(const bf16x8*)(ph0 + kc * 32);
    bf16x8 al0 = *(const bf16x8*)(pl0 + kc * 32);
    bf16x8 ah1 = *(const bf16x8*)(ph0 + 16 * 128 + kc * 32);
    bf16x8 al1 = *(const bf16x8*)(pl0 + 16 * 128 + kc * 32);
    int k0 = kc * 32 + quad * 8;
#pragma unroll
    for (int tt = 0; tt < 8; ++tt) {
      int nn = tt * 16 + m16;
      bf16x8 bh = *(const bf16x8*)(Bh + nn * 128 + k0);
      bf16x8 bl = *(const bf16x8*)(Bl + nn * 128 + k0);
      acc0[tt] = __builtin_amdgcn_mfma_f32_16x16x32_bf16(ah0, bh, acc0[tt], 0, 0, 0);
      acc0[tt] = __builtin_amdgcn_mfma_f32_16x16x32_bf16(ah0, bl, acc0[tt], 0, 0, 0);
      acc0[tt] = __builtin_amdgcn_mfma_f32_16x16x32_bf16(al0, bh, acc0[tt], 0, 0, 0);
      acc1[tt] = __builtin_amdgcn_mfma_f32_16x16x32_bf16(ah1, bh, acc1[tt], 0, 0, 0);
      acc1[tt] = __builtin_amdgcn_mfma_f32_16x16x32_bf16(ah1, bl, acc1[tt], 0, 0, 0);
      acc1[tt] = __builtin_amdgcn_mfma_f32_16x16x32_bf16(al1, bh, acc1[tt], 0, 0, 0);
    }
  }
  int rr = t >> 2;               // 0..63
  int cb = (t & 3) * 32;         // col base
  int grow = rowbase + ((rr >> 4) << 5) + (rr & 15);
#pragma unroll
  for (int ph = 0; ph < 2; ++ph) {
    if (ph) __syncthreads();
#pragma unroll
    for (int tt = 0; tt < 8; ++tt)
#pragma unroll
      for (int r = 0; r < 4; ++r)
        C[wv * 16 + quad * 4 + r][tt * 16 + m16] = ph ? acc1[tt][r] : acc0[tt][r];
    __syncthreads();
    const float* crow = &C[rr][cb];
    __half2 o[16];
#pragma unroll
    for (int i = 0; i < 16; ++i) {
      __half2 h;
      h.x = __float2half_rn(crow[2 * i]);
      h.y = __float2half_rn(crow[2 * i + 1]);
      o[i] = h;
    }
    uint4* dst = (uint4*)(XW + (size_t)(grow + ph * 16) * 128 + cb);
    dst[0] = ((const uint4*)o)[0];
    dst[1] = ((const uint4*)o)[1];
    dst[2] = ((const uint4*)o)[2];
    dst[3] = ((const uint4*)o)[3];
  }
}

// ---------------- CSR aggregation + bias + relu -> bf16 hi/lo H ----------------
// wave per node; 16 lanes cooperate per edge row (uint4 = 16B/lane), 4 edges
// in flight per wave via lane-groups; butterfly-reduce groups at the end.
__global__ __launch_bounds__(256) void agg_csr(const __half* __restrict__ XW,
    const int* __restrict__ rowstart, const unsigned int* __restrict__ epack,
    const float* __restrict__ dis, const float* __restrict__ bias,
    unsigned short* __restrict__ Hh, unsigned short* __restrict__ Hl, int n) {
  int w = (blockIdx.x * 256 + threadIdx.x) >> 6;
  int l = threadIdx.x & 63;
  if (w >= n) return;
  int g = l >> 4;         // edge group 0..3
  int j = l & 15;         // column slice (8 cols each)
  float A[8];
#pragma unroll
  for (int k = 0; k < 8; ++k) A[k] = 0.f;
  int p = rowstart[w], p1 = rowstart[w + 1];
  for (; p < p1; p += 16) {
    int idx[4]; float wt[4];
#pragma unroll
    for (int u = 0; u < 4; ++u) {
      int pe = p + u * 4 + g;
      unsigned int rec = epack[pe];        // epack padded +16: safe overread
      bool inb = pe < p1;
      idx[u] = inb ? (int)(rec & 0xffffu) : w;
      wt[u] = inb ? h2f_bits((unsigned short)(rec >> 16)) : 0.f;
    }
    uint4 r[4];
#pragma unroll
    for (int u = 0; u < 4; ++u)
      r[u] = *(const uint4*)(XW + (size_t)idx[u] * 128 + j * 8);
#pragma unroll
    for (int u = 0; u < 4; ++u) {
      const __half2* h2 = (const __half2*)&r[u];
#pragma unroll
      for (int q = 0; q < 4; ++q) {
        A[2 * q + 0] = fmaf(wt[u], __low2float(h2[q]), A[2 * q + 0]);
        A[2 * q + 1] = fmaf(wt[u], __high2float(h2[q]), A[2 * q + 1]);
      }
    }
  }
  // reduce the 4 edge-groups (lanes l, l^16, l^32, l^48 hold same columns)
#pragma unroll
  for (int k = 0; k < 8; ++k) {
    A[k] += __shfl_xor(A[k], 16, 64);
    A[k] += __shfl_xor(A[k], 32, 64);
  }
  if (g == 0) {
    float dd = dis[w];
    float d2 = dd * dd;
    uint4 sr = *(const uint4*)(XW + (size_t)w * 128 + j * 8);
    const __half2* sh2 = (const __half2*)&sr;
    float4 b0 = *(const float4*)(bias + j * 8);
    float4 b1 = *(const float4*)(bias + j * 8 + 4);
    float bb[8] = {b0.x, b0.y, b0.z, b0.w, b1.x, b1.y, b1.z, b1.w};
    unsigned short oh[8], ol[8];
#pragma unroll
    for (int k = 0; k < 8; ++k) {
      float sv = (k & 1) ? __high2float(sh2[k >> 1]) : __low2float(sh2[k >> 1]);
      float v = fmaxf(A[k] + d2 * sv + bb[k], 0.f);
      oh[k] = f2b(v);
      ol[k] = f2b(v - b2f(oh[k]));
    }
    *(uint4*)(Hh + (size_t)w * 128 + j * 8) = *(const uint4*)oh;
    *(uint4*)(Hl + (size_t)w * 128 + j * 8) = *(const uint4*)ol;
  }
}

// ---------------- final layer ----------------
__global__ __launch_bounds__(256) void gemm_w8(const unsigned short* __restrict__ Hh,
    const unsigned short* __restrict__ Hl, const float* __restrict__ W8,
    float* __restrict__ XW2, int n) {
  __shared__ float w[256];
  int t = threadIdx.x;
  w[t] = W8[t];
  __syncthreads();
  int r = blockIdx.x * 256 + t;
  if (r >= n) return;
  const unsigned short* hh = Hh + (size_t)r * 128;
  const unsigned short* hl = Hl + (size_t)r * 128;
  float a0 = 0.f, a1 = 0.f;
#pragma unroll
  for (int k = 0; k < 128; k += 4) {
    ushort4 uh = *(const ushort4*)(hh + k);
    ushort4 ul = *(const ushort4*)(hl + k);
    float h0 = b2f(uh.x) + b2f(ul.x);
    float h1 = b2f(uh.y) + b2f(ul.y);
    float h2 = b2f(uh.z) + b2f(ul.z);
    float h3 = b2f(uh.w) + b2f(ul.w);
    a0 += h0 * w[2 * k + 0] + h1 * w[2 * k + 2] + h2 * w[2 * k + 4] + h3 * w[2 * k + 6];
    a1 += h0 * w[2 * k + 1] + h1 * w[2 * k + 3] + h2 * w[2 * k + 5] + h3 * w[2 * k + 7];
  }
  XW2[r * 2 + 0] = a0;
  XW2[r * 2 + 1] = a1;
}

__global__ __launch_bounds__(256) void agg_final(const float* __restrict__ XW2,
    const int* __restrict__ rowstart, const unsigned int* __restrict__ epack,
    const float* __restrict__ dis, const float* __restrict__ b8,
    float* __restrict__ out, int n) {
  int i = blockIdx.x * 256 + threadIdx.x;
  if (i >= n) return;
  float d = dis[i], d2 = d * d;
  float a0 = d2 * XW2[i * 2 + 0];
  float a1 = d2 * XW2[i * 2 + 1];
  int p1 = rowstart[i + 1];
  for (int p = rowstart[i]; p < p1; ++p) {
    unsigned int rec = epack[p];
    int s = (int)(rec & 0xffffu);
    float wt = h2f_bits((unsigned short)(rec >> 16));
    a0 = fmaf(wt, XW2[s * 2 + 0], a0);
    a1 = fmaf(wt, XW2[s * 2 + 1], a1);
  }
  out[i * 2 + 0] = a0 + b8[0];
  out[i * 2 + 1] = a1 + b8[1];
}

// ---------------- launcher ----------------
static inline char* alignp(char* p) {
  return (char*)(((uintptr_t)p + 255) & ~(uintptr_t)255);
}

extern "C" void kernel_launch(void* const* d_in, const int* in_sizes, int n_in,
                              void* d_out, int out_size, void* d_ws, size_t ws_size,
                              hipStream_t stream) {
  (void)in_sizes; (void)n_in; (void)out_size; (void)ws_size;
  const int n = NN, e = NE;
  const float* x  = (const float*)d_in[0];
  const int*   ei = (const int*)d_in[1];
  const float* ea = (const float*)d_in[2];
  const float* W1 = (const float*)d_in[3];
  const float* b1 = (const float*)d_in[4];
  const float* Wm = (const float*)d_in[5];
  const float* bm = (const float*)d_in[6];
  const float* W8 = (const float*)d_in[7];
  const float* b8 = (const float*)d_in[8];
  float* out = (float*)d_out;

  char* w = (char*)d_ws;
  int*   flag   = (int*)w;            w = alignp(w + 4);
  int*   part   = (int*)w;            w = alignp(w + SCAN_NB * 4);
  unsigned long long* dc = (unsigned long long*)w; w = alignp(w + (size_t)n * 8);
  float* dis    = (float*)w;          w = alignp(w + (size_t)n * 4);
  int*   cnt    = (int*)w;            w = alignp(w + (size_t)n * 4);
  int*   rowst  = (int*)w;            w = alignp(w + (size_t)(n + 1) * 4);
  unsigned short* ord = (unsigned short*)w;  w = alignp(w + (size_t)e * 2);
  unsigned int* epack = (unsigned int*)w;    w = alignp(w + (size_t)(e + 16) * 4);
  unsigned short* Hh  = (unsigned short*)w;  w = alignp(w + (size_t)MP * 128 * 2);
  unsigned short* Hl  = (unsigned short*)w;  w = alignp(w + (size_t)MP * 128 * 2);
  unsigned short* Wth = (unsigned short*)w;  w = alignp(w + (size_t)7 * 16384 * 2);
  unsigned short* Wtl = (unsigned short*)w;  w = alignp(w + (size_t)7 * 16384 * 2);
  __half* XW  = (__half*)w;           w = alignp(w + (size_t)MP * 128 * 2);
  float* XW2  = (float*)w;            w = alignp(w + (size_t)MP * 2 * 4);

  const int GN = (n + 255) / 256;
  const int GE = (e + 255) / 256;

  prep_fused<<<SCAN_NB + CVT_XB + CVT_WB, 256, 0, stream>>>(
      ei, flag, dc, x, Hh, Hl, W1, Wm, Wth, Wtl, n, n * 128);
  prep_hist<<<GE, 256, 0, stream>>>(ei, flag, ea, dc, ord, e);
  prep_dis_part<<<SCAN_NB, 256, 0, stream>>>(dc, dis, cnt, part, n);
  scan_apply<<<SCAN_NB, 256, 0, stream>>>(cnt, part, rowst, n, e);
  prep_scatter<<<GE, 256, 0, stream>>>(ei, flag, ea, dis, rowst, ord, epack, e);

  for (int l = 0; l < 7; ++l) {
    const unsigned short* Bh = Wth + (size_t)l * 16384;
    const unsigned short* Bl = Wtl + (size_t)l * 16384;
    const float* bl = (l == 0) ? b1 : bm + (size_t)(l - 1) * 128;
    gemm_mfma<<<MP / 128, 256, 0, stream>>>(Hh, Hl, Bh, Bl, XW);
    agg_csr<<<(n * 64 + 255) / 256, 256, 0, stream>>>(XW, rowst, epack, dis, bl, Hh, Hl, n);
  }
  gemm_w8<<<GN, 256, 0, stream>>>(Hh, Hl, W8, XW2, n);
  agg_final<<<GN, 256, 0, stream>>>(XW2, rowst, epack, dis, b8, out, n);
}